// Round 1
// baseline (72.519 us; speedup 1.0000x reference)
//
#include <hip/hip_runtime.h>

#define D 1024
#define EPS 1e-6f

// One block (256 threads) per token row. Each thread owns 4 consecutive
// floats (float4) of the row -> whole row resident in registers, single
// HBM pass: read emb + curv, write out.
__global__ __launch_bounds__(256) void fieldnorm_kernel(
    const float* __restrict__ emb,
    const float* __restrict__ curv,
    const float* __restrict__ gamma,
    const float* __restrict__ beta,
    const float* __restrict__ cscale,
    float* __restrict__ out)
{
    const int row = blockIdx.x;            // 0 .. B*S-1
    const int tid = threadIdx.x;           // 0 .. 255
    const long long base = (long long)row * D;

    const float4 x = reinterpret_cast<const float4*>(emb + base)[tid];
    const float4 c = reinterpret_cast<const float4*>(curv + base)[tid];

    float sx  = (x.x + x.y) + (x.z + x.w);
    float sx2 = (x.x * x.x + x.y * x.y) + (x.z * x.z + x.w * x.w);
    float sc2 = (c.x * c.x + c.y * c.y) + (c.z * c.z + c.w * c.w);

    // Wave-level tree reduce (64 lanes).
    #pragma unroll
    for (int off = 32; off > 0; off >>= 1) {
        sx  += __shfl_down(sx,  off, 64);
        sx2 += __shfl_down(sx2, off, 64);
        sc2 += __shfl_down(sc2, off, 64);
    }

    // Cross-wave reduce via LDS (4 waves/block).
    __shared__ float red[3][4];
    const int wave = tid >> 6;
    if ((tid & 63) == 0) {
        red[0][wave] = sx;
        red[1][wave] = sx2;
        red[2][wave] = sc2;
    }
    __syncthreads();
    sx  = (red[0][0] + red[0][1]) + (red[0][2] + red[0][3]);
    sx2 = (red[1][0] + red[1][1]) + (red[1][2] + red[1][3]);
    sc2 = (red[2][0] + red[2][1]) + (red[2][2] + red[2][3]);

    const float inv_d = 1.0f / (float)D;
    const float mean  = sx * inv_d;
    const float var   = sx2 * inv_d - mean * mean;
    const float rstd  = rsqrtf(var + EPS);
    const float cmag  = sqrtf(sc2 + EPS);
    const float fac   = 1.0f / (1.0f + cscale[0] * cmag);
    const float s     = rstd * fac;

    const float4 g = reinterpret_cast<const float4*>(gamma)[tid];
    const float4 b = reinterpret_cast<const float4*>(beta)[tid];

    float4 o;
    o.x = (x.x - mean) * s * g.x + b.x;
    o.y = (x.y - mean) * s * g.y + b.y;
    o.z = (x.z - mean) * s * g.z + b.z;
    o.w = (x.w - mean) * s * g.w + b.w;
    reinterpret_cast<float4*>(out + base)[tid] = o;
}

extern "C" void kernel_launch(void* const* d_in, const int* in_sizes, int n_in,
                              void* d_out, int out_size, void* d_ws, size_t ws_size,
                              hipStream_t stream) {
    const float* emb    = (const float*)d_in[0];
    const float* curv   = (const float*)d_in[1];
    const float* gamma  = (const float*)d_in[2];
    const float* beta   = (const float*)d_in[3];
    const float* cscale = (const float*)d_in[4];
    float* out = (float*)d_out;

    const int rows = out_size / D;   // B*S = 32768
    fieldnorm_kernel<<<rows, 256, 0, stream>>>(emb, curv, gamma, beta, cscale, out);
}

// Round 3
// 60.747 us; speedup vs baseline: 1.1938x; 1.1938x over previous
//
#include <hip/hip_runtime.h>

#define D 1024
#define EPS 1e-6f

// Native clang vector type: accepted by __builtin_nontemporal_{load,store},
// lowers to global_{load,store}_dwordx4.
typedef float floatx4 __attribute__((ext_vector_type(4)));

// One WAVE (64 lanes) per token row; 4 independent waves per 256-thread
// block (no __syncthreads, no LDS). Each lane owns 16 elements as 4x float4
// at float4-indices {lane, lane+64, lane+128, lane+192} -> coalesced.
// Reduction is a pure in-register __shfl_xor butterfly (all lanes get sum).
// Output uses non-temporal stores so the write stream does not evict the
// (L3-resident) inputs from Infinity Cache.
__global__ __launch_bounds__(256) void fieldnorm_kernel(
    const float* __restrict__ emb,
    const float* __restrict__ curv,
    const float* __restrict__ gamma,
    const float* __restrict__ beta,
    const float* __restrict__ cscale,
    float* __restrict__ out)
{
    const int wave = threadIdx.x >> 6;          // 0..3
    const int lane = threadIdx.x & 63;
    const int row  = blockIdx.x * 4 + wave;     // 0 .. B*S-1
    const long long base = (long long)row * D;

    const floatx4* __restrict__ xp = reinterpret_cast<const floatx4*>(emb + base);
    const floatx4* __restrict__ cp = reinterpret_cast<const floatx4*>(curv + base);

    // Load the full row of embeddings into registers (16 floats/lane).
    floatx4 x[4];
    #pragma unroll
    for (int j = 0; j < 4; ++j) x[j] = xp[lane + 64 * j];

    // Curvature: load, accumulate sum of squares, release registers.
    float sc2 = 0.0f;
    #pragma unroll
    for (int j = 0; j < 4; ++j) {
        const floatx4 c = cp[lane + 64 * j];
        sc2 += (c.x * c.x + c.y * c.y) + (c.z * c.z + c.w * c.w);
    }

    float sx = 0.0f, sx2 = 0.0f;
    #pragma unroll
    for (int j = 0; j < 4; ++j) {
        sx  += (x[j].x + x[j].y) + (x[j].z + x[j].w);
        sx2 += (x[j].x * x[j].x + x[j].y * x[j].y)
             + (x[j].z * x[j].z + x[j].w * x[j].w);
    }

    // Wave-wide butterfly reduce: every lane ends with the full sums.
    #pragma unroll
    for (int off = 32; off > 0; off >>= 1) {
        sx  += __shfl_xor(sx,  off, 64);
        sx2 += __shfl_xor(sx2, off, 64);
        sc2 += __shfl_xor(sc2, off, 64);
    }

    const float inv_d = 1.0f / (float)D;
    const float mean  = sx * inv_d;
    const float var   = sx2 * inv_d - mean * mean;
    const float rstd  = rsqrtf(var + EPS);
    const float cmag  = sqrtf(sc2 + EPS);
    const float fac   = 1.0f / (1.0f + cscale[0] * cmag);
    const float s     = rstd * fac;

    const floatx4* __restrict__ gp = reinterpret_cast<const floatx4*>(gamma);
    const floatx4* __restrict__ bp = reinterpret_cast<const floatx4*>(beta);
    floatx4* __restrict__ op = reinterpret_cast<floatx4*>(out + base);

    #pragma unroll
    for (int j = 0; j < 4; ++j) {
        const int idx = lane + 64 * j;
        const floatx4 g = gp[idx];
        const floatx4 b = bp[idx];
        floatx4 o;
        o.x = (x[j].x - mean) * s * g.x + b.x;
        o.y = (x[j].y - mean) * s * g.y + b.y;
        o.z = (x[j].z - mean) * s * g.z + b.z;
        o.w = (x[j].w - mean) * s * g.w + b.w;
        __builtin_nontemporal_store(o, &op[idx]);
    }
}

extern "C" void kernel_launch(void* const* d_in, const int* in_sizes, int n_in,
                              void* d_out, int out_size, void* d_ws, size_t ws_size,
                              hipStream_t stream) {
    const float* emb    = (const float*)d_in[0];
    const float* curv   = (const float*)d_in[1];
    const float* gamma  = (const float*)d_in[2];
    const float* beta   = (const float*)d_in[3];
    const float* cscale = (const float*)d_in[4];
    float* out = (float*)d_out;

    const int rows = out_size / D;     // B*S = 32768
    fieldnorm_kernel<<<rows / 4, 256, 0, stream>>>(emb, curv, gamma, beta, cscale, out);
}